// Round 12
// baseline (629.809 us; speedup 1.0000x reference)
//
#include <hip/hip_runtime.h>
#include <hip/hip_bf16.h>
#include <math.h>

#define NNODES 100000
#define NEDGES 3200000
#define NBUK ((NNODES + 127) >> 7)   // 782 buckets of 128 nodes
#define NCHUNK 256
#define EPC (NEDGES / NCHUNK)        // 12500 edges per chunk

typedef float floatx2 __attribute__((ext_vector_type(2)));
typedef float f32x4 __attribute__((ext_vector_type(4)));
typedef short bf16x8 __attribute__((ext_vector_type(8)));

// ---- bf16 pack ----
__device__ __forceinline__ unsigned short f2bf(float x) {
    unsigned u = __float_as_uint(x);
    unsigned r = u + 0x7FFFu + ((u >> 16) & 1u);
    return (unsigned short)(r >> 16);
}

// ---- fp8 e4m3 packed accumulate (gfx950 HW converts) ----
__device__ __forceinline__ void acc8_fp8(uint2 v, floatx2* a) {
    a[0] += __builtin_amdgcn_cvt_pk_f32_fp8(v.x, false);
    a[1] += __builtin_amdgcn_cvt_pk_f32_fp8(v.x, true);
    a[2] += __builtin_amdgcn_cvt_pk_f32_fp8(v.y, false);
    a[3] += __builtin_amdgcn_cvt_pk_f32_fp8(v.y, true);
}
__device__ __forceinline__ void acc4_fp8(unsigned v, floatx2* a) {
    a[0] += __builtin_amdgcn_cvt_pk_f32_fp8(v, false);
    a[1] += __builtin_amdgcn_cvt_pk_f32_fp8(v, true);
}

// ---------------- pass 1: per-chunk bucket histogram (LDS, int4 reads) + weight prep ----------------
__global__ __launch_bounds__(1024) void hist_prep_kernel(const int* __restrict__ dst,
                                                         int* __restrict__ hist,
                                                         const float* __restrict__ W1,
                                                         const float* __restrict__ W2,
                                                         unsigned short* __restrict__ Wt1,
                                                         unsigned short* __restrict__ Wt2) {
    int c = blockIdx.x, t = threadIdx.x;
    if (c >= NCHUNK) {           // 24 prep blocks: transpose + bf16 W1, W2
        int i = (c - NCHUNK) * 1024 + t;     // 0..24575
        if (i < 128 * 128) {
            int k = i >> 7, n = i & 127;
            Wt1[n * 128 + k] = f2bf(W1[i]);
        } else {
            int j = i - 128 * 128;
            int k = j >> 6, n = j & 63;
            Wt2[n * 128 + k] = f2bf(W2[j]);
        }
        return;
    }
    __shared__ int h[NBUK];
    for (int i = t; i < NBUK; i += 1024) h[i] = 0;
    __syncthreads();
    const int4* d4 = (const int4*)(dst + c * EPC);
    for (int i = t; i < EPC / 4; i += 1024) {
        int4 d = d4[i];
        atomicAdd(&h[d.x >> 7], 1);
        atomicAdd(&h[d.y >> 7], 1);
        atomicAdd(&h[d.z >> 7], 1);
        atomicAdd(&h[d.w >> 7], 1);
    }
    __syncthreads();
    for (int i = t; i < NBUK; i += 1024)
        hist[c * NBUK + i] = h[i];
}

// ---------------- pass 2: col scan over chunks + bucket scan -> bstart (one kernel) ----------------
__global__ __launch_bounds__(1024) void scan_kernel(int* __restrict__ hist, int* __restrict__ bstart,
                                                    int* __restrict__ row_start,
                                                    float* __restrict__ smalls) {
    __shared__ int s[1024];
    int t = threadIdx.x;
    if (t < 592) smalls[t] = 0.0f;   // colsum(8) ata(64) ge(512)
    int run = 0;
    if (t < NBUK) {
        for (int c = 0; c < NCHUNK; c++) {
            int idx = c * NBUK + t;          // coalesced across t
            int v = hist[idx];
            hist[idx] = run;
            run += v;
        }
    }
    s[t] = (t < NBUK) ? run : 0;
    __syncthreads();
    for (int off = 1; off < 1024; off <<= 1) {
        int x = (t >= off) ? s[t - off] : 0;
        __syncthreads();
        s[t] += x;
        __syncthreads();
    }
    if (t < NBUK) bstart[t] = s[t] - run;
    if (t == 0) {
        bstart[NBUK] = NEDGES;
        row_start[NNODES] = NEDGES;
    }
}

// ---------------- pass 3: deterministic scatter into bucket order (LDS cursors, int4 reads) ----
__global__ __launch_bounds__(1024) void chunk_scatter_kernel(const int* __restrict__ src,
                                                             const int* __restrict__ dst,
                                                             const int* __restrict__ hist,
                                                             const int* __restrict__ bstart,
                                                             int* __restrict__ ebuk) {
    __shared__ int cur[NBUK];
    int c = blockIdx.x, t = threadIdx.x;
    for (int i = t; i < NBUK; i += 1024)
        cur[i] = bstart[i] + hist[c * NBUK + i];
    __syncthreads();
    const int4* s4 = (const int4*)(src + c * EPC);
    const int4* d4 = (const int4*)(dst + c * EPC);
    for (int i = t; i < EPC / 4; i += 1024) {
        int4 s = s4[i];
        int4 d = d4[i];
        int p0 = atomicAdd(&cur[d.x >> 7], 1);
        ebuk[p0] = s.x | ((d.x & 127) << 20);
        int p1 = atomicAdd(&cur[d.y >> 7], 1);
        ebuk[p1] = s.y | ((d.y & 127) << 20);
        int p2 = atomicAdd(&cur[d.z >> 7], 1);
        ebuk[p2] = s.z | ((d.z & 127) << 20);
        int p3 = atomicAdd(&cur[d.w >> 7], 1);
        ebuk[p3] = s.w | ((d.w & 127) << 20);
    }
}

// ---------------- pass 4: per-bucket node counts, row_start, dinv, csr fill ----------------
__global__ __launch_bounds__(256) void build_kernel(const int* __restrict__ ebuk,
                                                    const int* __restrict__ bstart,
                                                    int* __restrict__ row_start,
                                                    float* __restrict__ dinv,
                                                    int* __restrict__ csr) {
    __shared__ int cnt[128];
    __shared__ int scn[128];
    __shared__ int cur[128];
    int b = blockIdx.x;
    int t = threadIdx.x;
    int s0 = bstart[b], s1 = bstart[b + 1];
    if (t < 128) cnt[t] = 0;
    __syncthreads();
    for (int i = s0 + t; i < s1; i += 256)
        atomicAdd(&cnt[(ebuk[i] >> 20) & 127], 1);
    __syncthreads();
    if (t < 128) scn[t] = cnt[t];
    __syncthreads();
#pragma unroll
    for (int off = 1; off < 128; off <<= 1) {
        int x = (t < 128 && t >= off) ? scn[t - off] : 0;
        __syncthreads();
        if (t < 128) scn[t] += x;
        __syncthreads();
    }
    int node = b * 128 + t;
    if (t < 128) {
        int rs = s0 + scn[t] - cnt[t];
        cur[t] = rs;
        if (node < NNODES) {
            row_start[node] = rs;
            dinv[node] = rsqrtf((float)cnt[t] + 1.0f);
        }
    }
    __syncthreads();
    for (int i = s0 + t; i < s1; i += 256) {
        int v = ebuk[i];
        int pos = atomicAdd(&cur[(v >> 20) & 127], 1);
        csr[pos] = v & 0xFFFFF;
    }
}

// ---------------- MFMA GEMM1: stage1(fp8) = dinv * (X @ W1), fp32 A ----------------
__global__ __launch_bounds__(256) void gemm1_mfma_kernel(const float* __restrict__ A,
                                                         const unsigned short* __restrict__ Wt,
                                                         const float* __restrict__ rowscale,
                                                         unsigned char* __restrict__ stage) {
    constexpr int KIN = 128, KOUT = 128;
    constexpr int LDK = KIN + 8;          // bf16 elems
    constexpr int LDC = KOUT + 4;         // fp32 elems
    constexpr int SH_AB = (64 + KOUT) * LDK * 2;
    constexpr int SH_C  = 64 * LDC * 4;
    constexpr int SH = SH_AB > SH_C ? SH_AB : SH_C;
    __shared__ char shbuf[SH];
    unsigned short* As = (unsigned short*)shbuf;
    unsigned short* Ws = As + 64 * LDK;
    float* Cs = (float*)shbuf;
    int t = threadIdx.x;
    int block_row = blockIdx.x * 64;

    for (int idx = t; idx < KOUT * (KIN / 8); idx += 256) {
        int n = idx / (KIN / 8), c = idx % (KIN / 8);
        *(uint4*)(Ws + n * LDK + c * 8) = *(const uint4*)(Wt + n * KIN + c * 8);
    }
    for (int idx = t; idx < 64 * (KIN / 4); idx += 256) {
        int r = idx / (KIN / 4), c = idx % (KIN / 4);
        float4 v = make_float4(0.f, 0.f, 0.f, 0.f);
        if (block_row + r < NNODES)
            v = *(const float4*)(A + (size_t)(block_row + r) * KIN + c * 4);
        unsigned p0 = (unsigned)f2bf(v.x) | ((unsigned)f2bf(v.y) << 16);
        unsigned p1 = (unsigned)f2bf(v.z) | ((unsigned)f2bf(v.w) << 16);
        *(uint2*)(As + r * LDK + c * 4) = make_uint2(p0, p1);
    }
    __syncthreads();

    int wv = t >> 6, lane = t & 63;
    int r0 = wv * 16;
    int m = lane & 15, q = lane >> 4;
    constexpr int NT = KOUT / 16;
    constexpr int KS = KIN / 32;
    f32x4 acc[NT];
#pragma unroll
    for (int nt = 0; nt < NT; nt++) acc[nt] = (f32x4)(0.f);
    bf16x8 afr[KS];
#pragma unroll
    for (int ks = 0; ks < KS; ks++)
        afr[ks] = *(bf16x8*)(As + (r0 + m) * LDK + ks * 32 + q * 8);
#pragma unroll
    for (int nt = 0; nt < NT; nt++) {
#pragma unroll
        for (int ks = 0; ks < KS; ks++) {
            bf16x8 b = *(bf16x8*)(Ws + (nt * 16 + m) * LDK + ks * 32 + q * 8);
            acc[nt] = __builtin_amdgcn_mfma_f32_16x16x32_bf16(afr[ks], b, acc[nt], 0, 0, 0);
        }
    }
    __syncthreads();
#pragma unroll
    for (int nt = 0; nt < NT; nt++)
#pragma unroll
        for (int j = 0; j < 4; j++)
            Cs[(r0 + q * 4 + j) * LDC + nt * 16 + m] = acc[nt][j];
    __syncthreads();
    for (int idx = t; idx < 64 * (KOUT / 4); idx += 256) {
        int r = idx / (KOUT / 4), c4 = idx % (KOUT / 4);
        int row = block_row + r;
        if (row < NNODES) {
            float4 v = *(float4*)(Cs + r * LDC + c4 * 4);
            float d = rowscale[row];
            int pk = __builtin_amdgcn_cvt_pk_fp8_f32(v.x * d, v.y * d, 0, false);
            pk = __builtin_amdgcn_cvt_pk_fp8_f32(v.z * d, v.w * d, pk, true);
            *(unsigned*)(stage + (size_t)row * KOUT + c4 * 4) = (unsigned)pk;
        }
    }
}

// ---------------- fused gather128 + MFMA gemm2: stage2(fp8) = dinv*(h1 @ W2) ----------------
// h1 row = relu((gather(stage1)+self)*dinv + b1), built in LDS (bf16) per 64-node tile.
__global__ __launch_bounds__(256) void g128_gemm2_kernel(
    const unsigned char* __restrict__ hs, const int* __restrict__ row_start,
    const int* __restrict__ csr, const float* __restrict__ dinv,
    const float* __restrict__ b1, const unsigned short* __restrict__ Wt2,
    unsigned char* __restrict__ stage2) {
    constexpr int KIN = 128, KOUT = 64;
    constexpr int LDK = KIN + 8;          // 136
    constexpr int LDC = KOUT + 4;         // 68
    __shared__ unsigned short As[64 * LDK];    // 17408 B (aliased by Cs)
    __shared__ unsigned short Ws[KOUT * LDK];  // 17408 B
    float* Cs = (float*)As;
    int t = threadIdx.x;
    int block_row = blockIdx.x * 64;
    int wv = t >> 6, lane = t & 63;

    // stage Wt2 -> LDS
    for (int idx = t; idx < KOUT * (KIN / 8); idx += 256) {
        int n = idx / (KIN / 8), cc = idx % (KIN / 8);
        *(uint4*)(Ws + n * LDK + cc * 8) = *(const uint4*)(Wt2 + n * KIN + cc * 8);
    }
    // gather phase: wave wv builds rows wv*16..wv*16+15 of the h1 tile
    {
        int g = lane >> 4, c = lane & 15;
        unsigned boff = (unsigned)c << 3;
        for (int i = 0; i < 16; i++) {
            int r = wv * 16 + i;
            int n = block_row + r;
            if (n >= NNODES) {
                if (g == 0) *(uint4*)(As + r * LDK + c * 8) = make_uint4(0, 0, 0, 0);
                continue;
            }
            int start = row_start[n], end = row_start[n + 1];
            floatx2 acc[4];
#pragma unroll
            for (int ii = 0; ii < 4; ii++) acc[ii] = (floatx2)(0.f);
            int w = (start + 3) & ~3;
            if (w > end) w = end;
            {
                int e2 = start + g;
                if (e2 < w) {
                    unsigned o = ((unsigned)csr[e2] << 7) + boff;
                    acc8_fp8(*(const uint2*)(hs + o), acc);
                }
            }
            for (; w + 32 <= end; w += 32) {
                int4 ca = *(const int4*)(csr + w + 4 * g);
                int4 cbv = *(const int4*)(csr + w + 16 + 4 * g);
                uint2 v0 = *(const uint2*)(hs + (((unsigned)ca.x  << 7) + boff));
                uint2 v1 = *(const uint2*)(hs + (((unsigned)ca.y  << 7) + boff));
                uint2 v2 = *(const uint2*)(hs + (((unsigned)ca.z  << 7) + boff));
                uint2 v3 = *(const uint2*)(hs + (((unsigned)ca.w  << 7) + boff));
                uint2 v4 = *(const uint2*)(hs + (((unsigned)cbv.x << 7) + boff));
                uint2 v5 = *(const uint2*)(hs + (((unsigned)cbv.y << 7) + boff));
                uint2 v6 = *(const uint2*)(hs + (((unsigned)cbv.z << 7) + boff));
                uint2 v7 = *(const uint2*)(hs + (((unsigned)cbv.w << 7) + boff));
                acc8_fp8(v0, acc); acc8_fp8(v1, acc); acc8_fp8(v2, acc); acc8_fp8(v3, acc);
                acc8_fp8(v4, acc); acc8_fp8(v5, acc); acc8_fp8(v6, acc); acc8_fp8(v7, acc);
            }
            for (; w + 16 <= end; w += 16) {
                int4 cs = *(const int4*)(csr + w + 4 * g);
                uint2 v0 = *(const uint2*)(hs + (((unsigned)cs.x << 7) + boff));
                uint2 v1 = *(const uint2*)(hs + (((unsigned)cs.y << 7) + boff));
                uint2 v2 = *(const uint2*)(hs + (((unsigned)cs.z << 7) + boff));
                uint2 v3 = *(const uint2*)(hs + (((unsigned)cs.w << 7) + boff));
                acc8_fp8(v0, acc); acc8_fp8(v1, acc); acc8_fp8(v2, acc); acc8_fp8(v3, acc);
            }
            for (int e2 = w + g; e2 < end; e2 += 4) {
                unsigned o = ((unsigned)csr[e2] << 7) + boff;
                acc8_fp8(*(const uint2*)(hs + o), acc);
            }
#pragma unroll
            for (int off = 16; off <= 32; off <<= 1)
#pragma unroll
                for (int ii = 0; ii < 4; ii++) {
                    acc[ii].x += __shfl_xor(acc[ii].x, off);
                    acc[ii].y += __shfl_xor(acc[ii].y, off);
                }
            if (g == 0) {
                floatx2 s[4];
#pragma unroll
                for (int ii = 0; ii < 4; ii++) s[ii] = (floatx2)(0.f);
                acc8_fp8(*(const uint2*)(hs + (((unsigned)n << 7) + boff)), s);
                float d = dinv[n];
                int j = c * 8;
                float4 bb0 = *(const float4*)(b1 + j);
                float4 bb1 = *(const float4*)(b1 + j + 4);
                float r0 = fmaxf((acc[0].x + s[0].x) * d + bb0.x, 0.f);
                float r1 = fmaxf((acc[0].y + s[0].y) * d + bb0.y, 0.f);
                float r2 = fmaxf((acc[1].x + s[1].x) * d + bb0.z, 0.f);
                float r3 = fmaxf((acc[1].y + s[1].y) * d + bb0.w, 0.f);
                float r4 = fmaxf((acc[2].x + s[2].x) * d + bb1.x, 0.f);
                float r5 = fmaxf((acc[2].y + s[2].y) * d + bb1.y, 0.f);
                float r6 = fmaxf((acc[3].x + s[3].x) * d + bb1.z, 0.f);
                float r7 = fmaxf((acc[3].y + s[3].y) * d + bb1.w, 0.f);
                uint4 p;
                p.x = (unsigned)f2bf(r0) | ((unsigned)f2bf(r1) << 16);
                p.y = (unsigned)f2bf(r2) | ((unsigned)f2bf(r3) << 16);
                p.z = (unsigned)f2bf(r4) | ((unsigned)f2bf(r5) << 16);
                p.w = (unsigned)f2bf(r6) | ((unsigned)f2bf(r7) << 16);
                *(uint4*)(As + r * LDK + c * 8) = p;
            }
        }
    }
    __syncthreads();
    // MFMA gemm2 on the LDS tile
    int r0 = wv * 16;
    int m = lane & 15, q = lane >> 4;
    constexpr int NT = KOUT / 16;   // 4
    constexpr int KS = KIN / 32;    // 4
    f32x4 acc[NT];
#pragma unroll
    for (int nt = 0; nt < NT; nt++) acc[nt] = (f32x4)(0.f);
    bf16x8 afr[KS];
#pragma unroll
    for (int ks = 0; ks < KS; ks++)
        afr[ks] = *(bf16x8*)(As + (r0 + m) * LDK + ks * 32 + q * 8);
#pragma unroll
    for (int nt = 0; nt < NT; nt++) {
#pragma unroll
        for (int ks = 0; ks < KS; ks++) {
            bf16x8 b = *(bf16x8*)(Ws + (nt * 16 + m) * LDK + ks * 32 + q * 8);
            acc[nt] = __builtin_amdgcn_mfma_f32_16x16x32_bf16(afr[ks], b, acc[nt], 0, 0, 0);
        }
    }
    __syncthreads();
#pragma unroll
    for (int nt = 0; nt < NT; nt++)
#pragma unroll
        for (int j = 0; j < 4; j++)
            Cs[(r0 + q * 4 + j) * LDC + nt * 16 + m] = acc[nt][j];
    __syncthreads();
    for (int idx = t; idx < 64 * (KOUT / 4); idx += 256) {
        int r = idx / (KOUT / 4), c4 = idx % (KOUT / 4);
        int row = block_row + r;
        if (row < NNODES) {
            float4 v = *(float4*)(Cs + r * LDC + c4 * 4);
            float d = dinv[row];
            int pk = __builtin_amdgcn_cvt_pk_fp8_f32(v.x * d, v.y * d, 0, false);
            pk = __builtin_amdgcn_cvt_pk_fp8_f32(v.z * d, v.w * d, pk, true);
            *(unsigned*)(stage2 + (size_t)row * KOUT + c4 * 4) = (unsigned)pk;
        }
    }
}

// ---------------- fused gather64 + attention + pooling (grid-stride 64-row tiles) ----------------
__global__ __launch_bounds__(256) void g64_attnpool_kernel(
    const unsigned char* __restrict__ hs, const int* __restrict__ row_start,
    const int* __restrict__ csr, const float* __restrict__ dinv,
    const float* __restrict__ b2,
    const float* __restrict__ Wf1, const float* __restrict__ bf1,
    const float* __restrict__ Wf2, const float* __restrict__ bf2,
    float* __restrict__ ge, float* __restrict__ ata, float* __restrict__ colsum) {
    __shared__ float h2S[64][68];
    __shared__ float a1S[64][68];
    __shared__ float attS[64][8];
    __shared__ float colS[8][64];
    int t = threadIdx.x;
    int wv = t >> 6, lane = t & 63;
    int d0 = t >> 6, j = t & 63;
    int de = t >> 3, ee = t & 7;
    float accge0 = 0.f, accge1 = 0.f, accata = 0.f, acccol = 0.f;
    int ntiles = (NNODES + 63) / 64;
    for (int tile = blockIdx.x; tile < ntiles; tile += gridDim.x) {
        int base = tile * 64;
        // ---- gather h2 tile (fp8 stage2 -> fp32 LDS) ----
        {
            int g = lane >> 4, c = lane & 15;
            unsigned boff = (unsigned)c << 2;
            for (int i = 0; i < 16; i++) {
                int r = wv * 16 + i;
                int n = base + r;
                if (n >= NNODES) {
                    if (g == 0) *(float4*)(&h2S[r][c * 4]) = make_float4(0.f, 0.f, 0.f, 0.f);
                    continue;
                }
                int start = row_start[n], end = row_start[n + 1];
                floatx2 acc[2];
                acc[0] = (floatx2)(0.f); acc[1] = (floatx2)(0.f);
                int w = (start + 3) & ~3;
                if (w > end) w = end;
                {
                    int e2 = start + g;
                    if (e2 < w) {
                        unsigned o = ((unsigned)csr[e2] << 6) + boff;
                        acc4_fp8(*(const unsigned*)(hs + o), acc);
                    }
                }
                for (; w + 32 <= end; w += 32) {
                    int4 ca = *(const int4*)(csr + w + 4 * g);
                    int4 cbv = *(const int4*)(csr + w + 16 + 4 * g);
                    unsigned v0 = *(const unsigned*)(hs + (((unsigned)ca.x  << 6) + boff));
                    unsigned v1 = *(const unsigned*)(hs + (((unsigned)ca.y  << 6) + boff));
                    unsigned v2 = *(const unsigned*)(hs + (((unsigned)ca.z  << 6) + boff));
                    unsigned v3 = *(const unsigned*)(hs + (((unsigned)ca.w  << 6) + boff));
                    unsigned v4 = *(const unsigned*)(hs + (((unsigned)cbv.x << 6) + boff));
                    unsigned v5 = *(const unsigned*)(hs + (((unsigned)cbv.y << 6) + boff));
                    unsigned v6 = *(const unsigned*)(hs + (((unsigned)cbv.z << 6) + boff));
                    unsigned v7 = *(const unsigned*)(hs + (((unsigned)cbv.w << 6) + boff));
                    acc4_fp8(v0, acc); acc4_fp8(v1, acc); acc4_fp8(v2, acc); acc4_fp8(v3, acc);
                    acc4_fp8(v4, acc); acc4_fp8(v5, acc); acc4_fp8(v6, acc); acc4_fp8(v7, acc);
                }
                for (; w + 16 <= end; w += 16) {
                    int4 cs = *(const int4*)(csr + w + 4 * g);
                    unsigned v0 = *(const unsigned*)(hs + (((unsigned)cs.x << 6) + boff));
                    unsigned v1 = *(const unsigned*)(hs + (((unsigned)cs.y << 6) + boff));
                    unsigned v2 = *(const unsigned*)(hs + (((unsigned)cs.z << 6) + boff));
                    unsigned v3 = *(const unsigned*)(hs + (((unsigned)cs.w << 6) + boff));
                    acc4_fp8(v0, acc); acc4_fp8(v1, acc); acc4_fp8(v2, acc); acc4_fp8(v3, acc);
                }
                for (int e2 = w + g; e2 < end; e2 += 4) {
                    unsigned o = ((unsigned)csr[e2] << 6) + boff;
                    acc4_fp8(*(const unsigned*)(hs + o), acc);
                }
#pragma unroll
                for (int off = 16; off <= 32; off <<= 1)
#pragma unroll
                    for (int ii = 0; ii < 2; ii++) {
                        acc[ii].x += __shfl_xor(acc[ii].x, off);
                        acc[ii].y += __shfl_xor(acc[ii].y, off);
                    }
                if (g == 0) {
                    floatx2 s[2];
                    s[0] = (floatx2)(0.f); s[1] = (floatx2)(0.f);
                    acc4_fp8(*(const unsigned*)(hs + (((unsigned)n << 6) + boff)), s);
                    float d = dinv[n];
                    int jj = c * 4;
                    float4 b4 = *(const float4*)(b2 + jj);
                    float4 res;
                    res.x = (acc[0].x + s[0].x) * d + b4.x;
                    res.y = (acc[0].y + s[0].y) * d + b4.y;
                    res.z = (acc[1].x + s[1].x) * d + b4.z;
                    res.w = (acc[1].y + s[1].y) * d + b4.w;
                    *(float4*)(&h2S[r][jj]) = res;
                }
            }
        }
        __syncthreads();
        // ---- phase 1: a1 = tanh(h2 @ Wf1 + bf1) ----
        {
            int cg = t & 15, rg = t >> 4;
            int jj = cg * 4, r0 = rg * 4;
            float4 b4 = *(const float4*)(bf1 + jj);
            float4 acc[4];
#pragma unroll
            for (int r = 0; r < 4; r++) acc[r] = b4;
#pragma unroll 4
            for (int k = 0; k < 64; k++) {
                float4 wv4 = *(const float4*)(Wf1 + (size_t)k * 64 + jj);
#pragma unroll
                for (int r = 0; r < 4; r++) {
                    float a = h2S[r0 + r][k];
                    acc[r].x += a * wv4.x; acc[r].y += a * wv4.y;
                    acc[r].z += a * wv4.z; acc[r].w += a * wv4.w;
                }
            }
#pragma unroll
            for (int r = 0; r < 4; r++) {
                a1S[r0 + r][jj]     = tanhf(acc[r].x);
                a1S[r0 + r][jj + 1] = tanhf(acc[r].y);
                a1S[r0 + r][jj + 2] = tanhf(acc[r].z);
                a1S[r0 + r][jj + 3] = tanhf(acc[r].w);
            }
        }
        __syncthreads();
        // ---- phase 2: att = exp(a1 @ Wf2 + bf2) ----
        {
            int cc = t & 7, r = t >> 3;
#pragma unroll
            for (int h = 0; h < 2; h++) {
                int rr = r + h * 32;
                float acc = bf2[cc];
                for (int k = 0; k < 64; k++)
                    acc += a1S[rr][k] * Wf2[(size_t)k * 8 + cc];
                float ev = (base + rr < NNODES) ? __expf(acc) : 0.f;
                attS[rr][cc] = ev;
                colS[cc][rr] = ev;
            }
        }
        __syncthreads();
        // ---- pooled accumulation ----
#pragma unroll 8
        for (int i = 0; i < 64; i++) {
            float hv = h2S[i][j];
            accge0 += attS[i][d0] * hv;
            accge1 += attS[i][d0 + 4] * hv;
        }
        if (t < 64) {
#pragma unroll 8
            for (int i = 0; i < 64; i++) accata += attS[i][de] * attS[i][ee];
        }
        if (t < 8) {
            float s = 0.f;
#pragma unroll
            for (int r = 0; r < 64; r++) s += colS[t][r];
            acccol += s;
        }
        __syncthreads();
    }
    atomicAdd(ge + d0 * 64 + j, accge0);
    atomicAdd(ge + (d0 + 4) * 64 + j, accge1);
    if (t < 64) atomicAdd(ata + de * 8 + ee, accata);
    if (t < 8) atomicAdd(colsum + t, acccol);
}

// ---------------- tiny epilogue ----------------
__global__ void final_kernel(const float* __restrict__ geacc, const float* __restrict__ ata,
                             const float* __restrict__ colsum, const float* __restrict__ Wl,
                             const float* __restrict__ bl, float* __restrict__ out) {
    __shared__ float geF[512];
    __shared__ float inv[8];
    __shared__ float logits[10];
    int t = threadIdx.x;
    if (t < 8) inv[t] = 1.0f / colsum[t];
    __syncthreads();
    for (int idx = t; idx < 512; idx += 64) {
        int d = idx >> 6;
        float v = geacc[idx] * inv[d];
        geF[idx] = v;
        out[idx] = v;                       // graph_embedding
    }
    __syncthreads();
    if (t == 0) {
        float pen = 0.f;
        for (int d = 0; d < 8; d++) {
            float s = 0.f;
            for (int e = 0; e < 8; e++) {
                float p = ata[d * 8 + e] * inv[d] * inv[e] - (d == e ? 1.0f : 0.0f);
                s += p * p;
            }
            pen += sqrtf(s);
        }
        out[512] = pen;                     // penalty
    }
    if (t < 10) {
        float acc = bl[t];
        for (int k = 0; k < 512; k++) acc += geF[k] * Wl[(size_t)k * 10 + t];
        logits[t] = acc;
    }
    __syncthreads();
    if (t == 0) {
        float m = -INFINITY;
        for (int l = 0; l < 10; l++) m = fmaxf(m, logits[l]);
        float s = 0.f;
        for (int l = 0; l < 10; l++) s += expf(logits[l] - m);
        float ls = logf(s);
        for (int l = 0; l < 10; l++) out[513 + l] = logits[l] - m - ls;  // log_softmax
    }
}

extern "C" void kernel_launch(void* const* d_in, const int* in_sizes, int n_in,
                              void* d_out, int out_size, void* d_ws, size_t ws_size,
                              hipStream_t stream) {
    const int* esrc = (const int*)d_in[0];
    const int* edst = esrc + NEDGES;
    const float* X   = (const float*)d_in[1];
    const float* W1  = (const float*)d_in[2];
    const float* b1  = (const float*)d_in[3];
    const float* W2  = (const float*)d_in[4];
    const float* b2  = (const float*)d_in[5];
    const float* Wf1 = (const float*)d_in[6];
    const float* bf1 = (const float*)d_in[7];
    const float* Wf2 = (const float*)d_in[8];
    const float* bf2 = (const float*)d_in[9];
    const float* Wl  = (const float*)d_in[10];
    const float* bl  = (const float*)d_in[11];
    float* out = (float*)d_out;

    // workspace layout
    float* ws     = (float*)d_ws;
    float* dinv   = ws;                               // N (padded to 100352)
    float* smalls = ws + 100352;                      // 1024
    float* colsum = smalls + 8;                       // 8
    float* ata    = smalls + 16;                      // 64
    float* geacc  = smalls + 80;                      // 512
    float* A = ws + 101376;                           // N*128 fp32 region
    float* B = A + (size_t)NNODES * 128;              // N*128 fp32 region
    int* row_start = (int*)(B + (size_t)NNODES * 128);// N+1 (padded 100352)
    int* bstart    = row_start + 100352;              // NBUK+1 (padded 1024)
    int* csr       = bstart + 1024;                   // E
    unsigned short* Wt1 = (unsigned short*)(csr + NEDGES);  // 128*128 bf16
    unsigned short* Wt2 = Wt1 + 128 * 128;                  // 64*128 bf16
    int* ebuk      = (int*)A;                         // E temp (consumed before gemm1 writes A)
    int* hist      = (int*)B;                         // NCHUNK*NBUK temp (consumed before stage2 writes B)
    unsigned char* stage1 = (unsigned char*)A;        // fp8 N*128 (gemm1 out, gather128 in)
    unsigned char* stage2 = (unsigned char*)B;        // fp8 N*64 (gemm2 out, gather64 in)

    // ---- CSR build + dinv + weight prep ----
    hist_prep_kernel<<<NCHUNK + 24, 1024, 0, stream>>>(edst, hist, W1, W2, Wt1, Wt2);
    scan_kernel<<<1, 1024, 0, stream>>>(hist, bstart, row_start, smalls);
    chunk_scatter_kernel<<<NCHUNK, 1024, 0, stream>>>(esrc, edst, hist, bstart, ebuk);
    build_kernel<<<NBUK, 256, 0, stream>>>(ebuk, bstart, row_start, dinv, csr);

    // ---- layer 1 GEMM: stage1 = fp8(dinv*(X@W1)) [MFMA] ----
    gemm1_mfma_kernel<<<(NNODES + 63) / 64, 256, 0, stream>>>(X, Wt1, dinv, stage1);

    // ---- fused gather128 + gemm2: stage2 = fp8(dinv*(h1@W2)) ----
    g128_gemm2_kernel<<<(NNODES + 63) / 64, 256, 0, stream>>>(stage1, row_start, csr, dinv,
                                                              b1, Wt2, stage2);

    // ---- fused gather64 + attention + pooling ----
    g64_attnpool_kernel<<<782, 256, 0, stream>>>(stage2, row_start, csr, dinv, b2,
                                                 Wf1, bf1, Wf2, bf2, geacc, ata, colsum);
    final_kernel<<<1, 64, 0, stream>>>(geacc, ata, colsum, Wl, bl, out);
}